// Round 1
// baseline (1312.577 us; speedup 1.0000x reference)
//
#include <hip/hip_runtime.h>

#define BB 16
#define PP 96
#define TT 128
#define VV 64
#define NN 16
#define DD 128
#define KPAD 132   // LDS row stride (floats) to break bank aliasing

__device__ __forceinline__ float dot4(float4 a, float4 b) {
    return a.x * b.x + a.y * b.y + a.z * b.z + a.w * b.w;
}

// ---------------------------------------------------------------------------
// K1: Wcomb = Wout @ Wkv  (so (x@Wkv^T+bkv)@Wout^T+bout == x@Wcomb^T+bcomb)
//     bcomb = Wout @ bkv + bout
// grid: 128 blocks x 128 threads
// ---------------------------------------------------------------------------
__global__ void combine_w(const float* __restrict__ Wout,
                          const float* __restrict__ Wkv,
                          const float* __restrict__ bkv,
                          const float* __restrict__ bout,
                          float* __restrict__ Wcomb,
                          float* __restrict__ bcomb) {
    int i = blockIdx.x, j = threadIdx.x;
    float acc = 0.f;
    for (int k = 0; k < DD; ++k) acc += Wout[i * DD + k] * Wkv[k * DD + j];
    Wcomb[i * DD + j] = acc;
    if (i == 0) {
        float b = bout[j];
        for (int k = 0; k < DD; ++k) b += Wout[j * DD + k] * bkv[k];
        bcomb[j] = b;
    }
}

// ---------------------------------------------------------------------------
// Generic row GEMM: Y[r] = X[r] @ W^T + bias for 64 rows per block, D=128.
// Block bl: b = bl / blocks_per_chunk, wi = bl % blocks_per_chunk
//   Xb = X + b*in_chunk_stride  + wi*64*D
//   Yb = Y + b*out_chunk_stride + wi*64*D
// Thread map: 32x8 -> each thread owns 2 rows x 16 cols.
// ---------------------------------------------------------------------------
__global__ __launch_bounds__(256) void gemm_rows(
    const float* __restrict__ X, const float* __restrict__ W,
    const float* __restrict__ bias, float* __restrict__ Y,
    int blocks_per_chunk, long in_chunk_stride, long out_chunk_stride) {
    int bl = blockIdx.x;
    int b = bl / blocks_per_chunk;
    int wi = bl % blocks_per_chunk;
    const float* Xb = X + (long)b * in_chunk_stride + (long)wi * 64 * DD;
    float* Yb = Y + (long)b * out_chunk_stride + (long)wi * 64 * DD;

    int t = threadIdx.x;
    int m0 = (t >> 3) * 2;
    int n0 = (t & 7) * 16;

    float acc0[16], acc1[16];
#pragma unroll
    for (int n = 0; n < 16; ++n) {
        float bv = bias[n0 + n];
        acc0[n] = bv; acc1[n] = bv;
    }
    for (int k = 0; k < DD; k += 4) {
        float4 x0 = *(const float4*)(Xb + (long)m0 * DD + k);
        float4 x1 = *(const float4*)(Xb + (long)(m0 + 1) * DD + k);
#pragma unroll
        for (int n = 0; n < 16; ++n) {
            float4 w = *(const float4*)(W + (long)(n0 + n) * DD + k);
            acc0[n] += dot4(x0, w);
            acc1[n] += dot4(x1, w);
        }
    }
#pragma unroll
    for (int c = 0; c < 4; ++c) {
        *(float4*)(Yb + (long)m0 * DD + n0 + 4 * c) =
            make_float4(acc0[4 * c], acc0[4 * c + 1], acc0[4 * c + 2], acc0[4 * c + 3]);
        *(float4*)(Yb + (long)(m0 + 1) * DD + n0 + 4 * c) =
            make_float4(acc1[4 * c], acc1[4 * c + 1], acc1[4 * c + 2], acc1[4 * c + 3]);
    }
}

// ---------------------------------------------------------------------------
// K3: fused attention, one block per (b,p). 256 threads.
//  - Ks = keys[b,32+p] @ Wkv^T + bkv           (in-block GEMM -> LDS)
//  - scores[v][n] = scale * q[v]·Ks[sel[v,n]]  (q read from d_out where K3a put it)
//  - softmax over n, weighted sum -> O (regs) -> LDS (reuse Ks)
//  - Y = O @ Wout^T + bout -> d_out[b, 32+p]   (overwrites the q staging rows)
// ---------------------------------------------------------------------------
__global__ __launch_bounds__(256) void attn_kernel(
    const float* __restrict__ keys, const int* __restrict__ ccc,
    const float* __restrict__ Wkv, const float* __restrict__ bkv,
    const float* __restrict__ Wout, const float* __restrict__ bout,
    float* __restrict__ out) {
    __shared__ float Ks[VV * KPAD];   // 33792 B
    __shared__ float sc[VV * NN];     // 4096 B
    __shared__ int   sel[VV * NN];    // 4096 B

    int bl = blockIdx.x;           // 0..B*P-1
    int b = bl / PP, p = bl % PP;
    int t = threadIdx.x;

    const float* Xb = keys + ((long)(b * TT + 32 + p) * VV) * DD;  // 64 raw key rows
    float* Qb = out + ((long)(b * TT + 32 + p) * VV) * DD;         // q staged here by K3a

    for (int i = t; i < VV * NN; i += 256) sel[i] = ccc[b * VV * NN + i];

    // ---- Ks = Xb @ Wkv^T + bkv ----
    {
        int m0 = (t >> 3) * 2, n0 = (t & 7) * 16;
        float acc0[16], acc1[16];
#pragma unroll
        for (int n = 0; n < 16; ++n) {
            float bv = bkv[n0 + n];
            acc0[n] = bv; acc1[n] = bv;
        }
        for (int k = 0; k < DD; k += 4) {
            float4 x0 = *(const float4*)(Xb + (long)m0 * DD + k);
            float4 x1 = *(const float4*)(Xb + (long)(m0 + 1) * DD + k);
#pragma unroll
            for (int n = 0; n < 16; ++n) {
                float4 w = *(const float4*)(Wkv + (long)(n0 + n) * DD + k);
                acc0[n] += dot4(x0, w);
                acc1[n] += dot4(x1, w);
            }
        }
#pragma unroll
        for (int n = 0; n < 16; ++n) {
            Ks[m0 * KPAD + n0 + n] = acc0[n];
            Ks[(m0 + 1) * KPAD + n0 + n] = acc1[n];
        }
    }
    __syncthreads();

    // ---- scores: thread t -> v = t>>2, n in [(t&3)*4, +4) ----
    {
        int v = t >> 2, nb = (t & 3) * 4;
        int se[4];
        float s[4] = {0.f, 0.f, 0.f, 0.f};
#pragma unroll
        for (int j = 0; j < 4; ++j) se[j] = sel[v * NN + nb + j];
        for (int k = 0; k < DD; k += 4) {
            float4 qv = *(const float4*)(Qb + (long)v * DD + k);
#pragma unroll
            for (int j = 0; j < 4; ++j) {
                float4 kv = *(const float4*)(&Ks[se[j] * KPAD + k]);
                s[j] += dot4(qv, kv);
            }
        }
#pragma unroll
        for (int j = 0; j < 4; ++j)
            sc[v * NN + nb + j] = s[j] * 0.08838834764831845f;  // 1/sqrt(128)
    }
    __syncthreads();

    // ---- softmax over n (N=16) per v ----
    if (t < VV) {
        float m = -1e30f;
#pragma unroll
        for (int n = 0; n < NN; ++n) m = fmaxf(m, sc[t * NN + n]);
        float e[NN], sum = 0.f;
#pragma unroll
        for (int n = 0; n < NN; ++n) { e[n] = __expf(sc[t * NN + n] - m); sum += e[n]; }
        float inv = 1.f / sum;
#pragma unroll
        for (int n = 0; n < NN; ++n) sc[t * NN + n] = e[n] * inv;
    }
    __syncthreads();

    // ---- O[v][d0..d0+31] in regs: thread t -> v = t>>2, d0 = (t&3)*32 ----
    float4 o[8];
    {
        int v = t >> 2, d0 = (t & 3) * 32;
#pragma unroll
        for (int c = 0; c < 8; ++c) o[c] = make_float4(0.f, 0.f, 0.f, 0.f);
#pragma unroll
        for (int n = 0; n < NN; ++n) {
            float w = sc[v * NN + n];
            const float* kr = &Ks[sel[v * NN + n] * KPAD + d0];
#pragma unroll
            for (int c = 0; c < 8; ++c) {
                float4 kv = *(const float4*)(kr + 4 * c);
                o[c].x += w * kv.x; o[c].y += w * kv.y;
                o[c].z += w * kv.z; o[c].w += w * kv.w;
            }
        }
    }
    __syncthreads();  // all reads of Ks done before overwrite
    {
        int v = t >> 2, d0 = (t & 3) * 32;
#pragma unroll
        for (int c = 0; c < 8; ++c)
            *(float4*)(&Ks[v * KPAD + d0 + 4 * c]) = o[c];
    }
    __syncthreads();

    // ---- final: Y = O @ Wout^T + bout ----
    {
        float* Yb = Qb;  // same rows: overwrite q staging with final output
        int m0 = (t >> 3) * 2, n0 = (t & 7) * 16;
        float acc0[16], acc1[16];
#pragma unroll
        for (int n = 0; n < 16; ++n) {
            float bv = bout[n0 + n];
            acc0[n] = bv; acc1[n] = bv;
        }
        for (int k = 0; k < DD; k += 4) {
            float4 x0 = *(const float4*)(&Ks[m0 * KPAD + k]);
            float4 x1 = *(const float4*)(&Ks[(m0 + 1) * KPAD + k]);
#pragma unroll
            for (int n = 0; n < 16; ++n) {
                float4 w = *(const float4*)(Wout + (long)(n0 + n) * DD + k);
                acc0[n] += dot4(x0, w);
                acc1[n] += dot4(x1, w);
            }
        }
#pragma unroll
        for (int c = 0; c < 4; ++c) {
            *(float4*)(Yb + (long)m0 * DD + n0 + 4 * c) =
                make_float4(acc0[4 * c], acc0[4 * c + 1], acc0[4 * c + 2], acc0[4 * c + 3]);
            *(float4*)(Yb + (long)(m0 + 1) * DD + n0 + 4 * c) =
                make_float4(acc1[4 * c], acc1[4 * c + 1], acc1[4 * c + 2], acc1[4 * c + 3]);
        }
    }
}

extern "C" void kernel_launch(void* const* d_in, const int* in_sizes, int n_in,
                              void* d_out, int out_size, void* d_ws, size_t ws_size,
                              hipStream_t stream) {
    const float* queries = (const float*)d_in[0];
    const float* keys    = (const float*)d_in[1];
    const int*   ccc     = (const int*)d_in[2];
    const float* Wq      = (const float*)d_in[3];
    const float* bq      = (const float*)d_in[4];
    const float* Wkv     = (const float*)d_in[5];
    const float* bkv     = (const float*)d_in[6];
    const float* Wout    = (const float*)d_in[7];
    const float* bout    = (const float*)d_in[8];
    float* out = (float*)d_out;

    float* Wcomb = (float*)d_ws;          // 16384 floats
    float* bcomb = Wcomb + DD * DD;       // 128 floats  (ws use: 66 KB total)

    // K1: fold Wout@Wkv for the t<32 passthrough rows
    combine_w<<<dim3(128), dim3(128), 0, stream>>>(Wout, Wkv, bkv, bout, Wcomb, bcomb);

    // K2: out[:, :32] = keys[:, :32] @ Wcomb^T + bcomb
    //     rows per batch chunk: 32*64 = 2048 -> 32 blocks/batch
    gemm_rows<<<dim3(BB * 32), dim3(256), 0, stream>>>(
        keys, Wcomb, bcomb, out,
        32, (long)TT * VV * DD, (long)TT * VV * DD);

    // K3a: q = queries @ Wq^T + bq, staged into out[b, 32+p] rows
    gemm_rows<<<dim3(BB * PP), dim3(256), 0, stream>>>(
        queries, Wq, bq, out + (long)32 * VV * DD,
        PP, (long)PP * VV * DD, (long)TT * VV * DD);

    // K3: fused k_last GEMM + gather-attention + output GEMM
    attn_kernel<<<dim3(BB * PP), dim3(256), 0, stream>>>(
        keys, ccc, Wkv, bkv, Wout, bout, out);
}

// Round 2
// 262.188 us; speedup vs baseline: 5.0063x; 5.0063x over previous
//
#include <hip/hip_runtime.h>

#define BB 16
#define PP 96
#define TT 128
#define VV 64
#define NN 16
#define DD 128
#define SB 136   // bf16 tile row stride (elems): 272 B/row, 16B-aligned, banks spread
#define ST 72    // KsT / A_sp row stride (elems): 144 B/row, 16B-aligned

typedef __bf16 bf16x8 __attribute__((ext_vector_type(8)));
typedef __bf16 bf16x4 __attribute__((ext_vector_type(4)));
typedef float  floatx4 __attribute__((ext_vector_type(4)));

#define MFMA16(a, b, c) __builtin_amdgcn_mfma_f32_16x16x32_bf16(a, b, c, 0, 0, 0)

// ---------------------------------------------------------------------------
// K1: Wcomb = Wout @ Wkv ; bcomb = Wout @ bkv + bout   (f32, tiny)
// ---------------------------------------------------------------------------
__global__ void combine_w(const float* __restrict__ Wout,
                          const float* __restrict__ Wkv,
                          const float* __restrict__ bkv,
                          const float* __restrict__ bout,
                          float* __restrict__ Wcomb,
                          float* __restrict__ bcomb) {
    int i = blockIdx.x, j = threadIdx.x;
    float acc = 0.f;
    for (int k = 0; k < DD; ++k) acc += Wout[i * DD + k] * Wkv[k * DD + j];
    Wcomb[i * DD + j] = acc;
    if (i == 0) {
        float b = bout[j];
        for (int k = 0; k < DD; ++k) b += Wout[j * DD + k] * bkv[k];
        bcomb[j] = b;
    }
}

// ---------------------------------------------------------------------------
// K1b: convert weights to bf16 (Wq | Wkv | Wout | Wcomb) into ws
// ---------------------------------------------------------------------------
__global__ void cvt_weights(const float* __restrict__ Wq,
                            const float* __restrict__ Wkv,
                            const float* __restrict__ Wout,
                            const float* __restrict__ Wcomb,
                            __bf16* __restrict__ o) {
    int i = blockIdx.x * 256 + threadIdx.x;  // 0..16383
    o[i]             = (__bf16)Wq[i];
    o[16384 + i]     = (__bf16)Wkv[i];
    o[32768 + i]     = (__bf16)Wout[i];
    o[49152 + i]     = (__bf16)Wcomb[i];
}

// ---------------------------------------------------------------------------
// 64x128 output GEMM helper: acc[nb] = A_strip @ B^T (K=128), A in LDS
// (stride sa), B row-major bf16 (stride sb; global weights or LDS tile).
// Wave w computes rows [16w,16w+16); nblocks tiles of 16 cols.
// A-frag: lane holds A[16w+lm][lq*8+32ks .. +8); B-frag: B[nb*16+lm][same k].
// D: col=lane&15, row=(lane>>4)*4+reg  (guide-verified m89/m91)
// ---------------------------------------------------------------------------
__device__ __forceinline__ void mm128(const __bf16* As, int sa,
                                      const __bf16* Bm, int sb,
                                      int w, int lm, int lq,
                                      floatx4* acc, int nblocks) {
    bf16x8 af[4];
#pragma unroll
    for (int ks = 0; ks < 4; ++ks)
        af[ks] = *(const bf16x8*)(As + (w * 16 + lm) * sa + lq * 8 + 32 * ks);
#pragma unroll
    for (int nb = 0; nb < 8; ++nb) {
        if (nb >= nblocks) break;
        acc[nb] = floatx4{0.f, 0.f, 0.f, 0.f};
#pragma unroll
        for (int ks = 0; ks < 4; ++ks) {
            bf16x8 bf = *(const bf16x8*)(Bm + (nb * 16 + lm) * sb + lq * 8 + 32 * ks);
            acc[nb] = MFMA16(af[ks], bf, acc[nb]);
        }
    }
}

// ---------------------------------------------------------------------------
// K2: passthrough rows  out[b, :32] = keys[b, :32] @ Wcomb^T + bcomb
// 512 blocks (16 batches x 32), 64 rows each.
// ---------------------------------------------------------------------------
__global__ __launch_bounds__(256, 4) void gemm_pass(
    const float* __restrict__ X, const __bf16* __restrict__ Wc,
    const float* __restrict__ bias, float* __restrict__ Y) {
    __shared__ __align__(16) __bf16 smX[64 * SB];
    int bl = blockIdx.x;
    int b = bl >> 5, wi = bl & 31;
    const float* Xb = X + ((long)b * TT * VV + wi * 64) * DD;
    float* Yb = Y + ((long)b * TT * VV + wi * 64) * DD;
    int t = threadIdx.x, w = t >> 6, L = t & 63, lm = L & 15, lq = L >> 4;

    {
        int r = t >> 2, c0 = (t & 3) * 32;
        const float4* s4 = (const float4*)(Xb + r * DD + c0);
#pragma unroll
        for (int i = 0; i < 8; ++i) {
            float4 v = s4[i];
            *(bf16x4*)(smX + r * SB + c0 + i * 4) =
                bf16x4{(__bf16)v.x, (__bf16)v.y, (__bf16)v.z, (__bf16)v.w};
        }
    }
    __syncthreads();

    floatx4 acc[8];
    mm128(smX, SB, Wc, DD, w, lm, lq, acc, 8);
#pragma unroll
    for (int nb = 0; nb < 8; ++nb) {
        float bv = bias[nb * 16 + lm];
#pragma unroll
        for (int r = 0; r < 4; ++r)
            Yb[(long)(w * 16 + lq * 4 + r) * DD + nb * 16 + lm] = acc[nb][r] + bv;
    }
}

// ---------------------------------------------------------------------------
// K3: fused attention, one block per (b,p), all GEMM phases on MFMA.
// ---------------------------------------------------------------------------
__global__ __launch_bounds__(256, 2) void attn_kernel(
    const float* __restrict__ queries, const float* __restrict__ keys,
    const int* __restrict__ ccc, const __bf16* __restrict__ Wb,
    const float* __restrict__ bq, const float* __restrict__ bkv,
    const float* __restrict__ bout, float* __restrict__ out) {
    __shared__ __align__(16) char lds[79872];
    __bf16* smKin = (__bf16*)lds;               // 17408: keys bf16 (later smS)
    __bf16* smQin = (__bf16*)(lds + 17408);     // 17408: queries -> q -> O
    __bf16* smKs  = (__bf16*)(lds + 34816);     // 17408: Ks row-major
    __bf16* smKsT = (__bf16*)(lds + 52224);     // 18432: Ks transposed (128 x 64)
    __bf16* smA   = (__bf16*)(lds + 70656);     //  9216: sparse attn matrix 64x64
    float*  smS   = (float*)lds;                // alias smKin: scores f32 64x64, stride 68
    __bf16* smO   = smQin;                      // alias smQin

    const __bf16* Wq_b   = Wb;
    const __bf16* Wkv_b  = Wb + 16384;
    const __bf16* Wout_b = Wb + 32768;

    int bl = blockIdx.x;
    int b = bl / PP, p = bl % PP;
    int t = threadIdx.x, w = t >> 6, L = t & 63, lm = L & 15, lq = L >> 4;

    const float* Kg = keys + ((long)(b * TT + 32 + p) * VV) * DD;
    const float* Qg = queries + ((long)(b * PP + p) * VV) * DD;
    float* Yg = out + ((long)(b * TT + 32 + p) * VV) * DD;

    // ---- P0: stage keys & queries tiles as bf16; zero A_sp ----
    {
        int r = t >> 2, c0 = (t & 3) * 32;
        const float4* k4 = (const float4*)(Kg + r * DD + c0);
        const float4* q4 = (const float4*)(Qg + r * DD + c0);
#pragma unroll
        for (int i = 0; i < 8; ++i) {
            float4 kv = k4[i], qv = q4[i];
            *(bf16x4*)(smKin + r * SB + c0 + i * 4) =
                bf16x4{(__bf16)kv.x, (__bf16)kv.y, (__bf16)kv.z, (__bf16)kv.w};
            *(bf16x4*)(smQin + r * SB + c0 + i * 4) =
                bf16x4{(__bf16)qv.x, (__bf16)qv.y, (__bf16)qv.z, (__bf16)qv.w};
        }
        for (int i = t; i < VV * ST / 2; i += 256) ((unsigned int*)smA)[i] = 0u;
    }
    __syncthreads();

    floatx4 acc[8];

    // ---- P1: q = Qin @ Wq^T + bq  (in-place, wave-private strip) ----
    mm128(smQin, SB, Wq_b, DD, w, lm, lq, acc, 8);
    __syncthreads();  // drain all smQin reads before in-place overwrite
#pragma unroll
    for (int nb = 0; nb < 8; ++nb) {
        float bv = bq[nb * 16 + lm];
#pragma unroll
        for (int r = 0; r < 4; ++r)
            smQin[(w * 16 + lq * 4 + r) * SB + nb * 16 + lm] = (__bf16)(acc[nb][r] + bv);
    }

    // ---- P2: Ks = Kin @ Wkv^T + bkv  -> smKs (row-major) + smKsT (transposed) ----
    mm128(smKin, SB, Wkv_b, DD, w, lm, lq, acc, 8);
#pragma unroll
    for (int nb = 0; nb < 8; ++nb) {
        float bv = bkv[nb * 16 + lm];
        bf16x4 tp;
#pragma unroll
        for (int r = 0; r < 4; ++r) {
            float vv = acc[nb][r] + bv;
            smKs[(w * 16 + lq * 4 + r) * SB + nb * 16 + lm] = (__bf16)vv;
            tp[r] = (__bf16)vv;
        }
        // (row, col) -> KsT[col][row]; 4 consecutive rows pack to one b64 write
        *(bf16x4*)(smKsT + (nb * 16 + lm) * ST + w * 16 + lq * 4) = tp;
    }
    __syncthreads();

    // ---- P3: S = q @ Ks^T  (64x64, f32 into smS aliasing smKin) ----
    mm128(smQin, SB, smKs, SB, w, lm, lq, acc, 4);
#pragma unroll
    for (int nb = 0; nb < 4; ++nb)
#pragma unroll
        for (int r = 0; r < 4; ++r)
            smS[(w * 16 + lq * 4 + r) * 68 + nb * 16 + lm] = acc[nb][r];
    __syncthreads();

    // ---- P4: gather + softmax + scatter into sparse A (dup-safe: 1 thread/row) ----
    if (t < VV) {
        const int4* cp = (const int4*)(ccc + (b * VV + t) * NN);
        int se[NN];
#pragma unroll
        for (int i = 0; i < 4; ++i) {
            int4 c4 = cp[i];
            se[4 * i] = c4.x; se[4 * i + 1] = c4.y; se[4 * i + 2] = c4.z; se[4 * i + 3] = c4.w;
        }
        float sc[NN], mx = -1e30f;
#pragma unroll
        for (int n = 0; n < NN; ++n) {
            sc[n] = smS[t * 68 + se[n]] * 0.08838834764831845f;
            mx = fmaxf(mx, sc[n]);
        }
        float sum = 0.f;
#pragma unroll
        for (int n = 0; n < NN; ++n) { sc[n] = __expf(sc[n] - mx); sum += sc[n]; }
        float inv = 1.f / sum;
#pragma unroll
        for (int n = 0; n < NN; ++n) {
            int u = se[n];
            float cur = (float)smA[t * ST + u];
            smA[t * ST + u] = (__bf16)(cur + sc[n] * inv);
        }
    }
    __syncthreads();

    // ---- P5: O = A_sp @ Ks  (K=64, B-frags from KsT) -> smO (alias smQin) ----
    {
        floatx4 accO[8];
        bf16x8 af2[2];
#pragma unroll
        for (int ks = 0; ks < 2; ++ks)
            af2[ks] = *(const bf16x8*)(smA + (w * 16 + lm) * ST + lq * 8 + 32 * ks);
#pragma unroll
        for (int nb = 0; nb < 8; ++nb) {
            accO[nb] = floatx4{0.f, 0.f, 0.f, 0.f};
#pragma unroll
            for (int ks = 0; ks < 2; ++ks) {
                bf16x8 bfr = *(const bf16x8*)(smKsT + (nb * 16 + lm) * ST + lq * 8 + 32 * ks);
                accO[nb] = MFMA16(af2[ks], bfr, accO[nb]);
            }
        }
#pragma unroll
        for (int nb = 0; nb < 8; ++nb)
#pragma unroll
            for (int r = 0; r < 4; ++r)
                smO[(w * 16 + lq * 4 + r) * SB + nb * 16 + lm] = (__bf16)accO[nb][r];
    }
    // no barrier needed: smO strip is wave-private (written P5, read P6, same wave)

    // ---- P6: Y = O @ Wout^T + bout -> global ----
    mm128(smO, SB, Wout_b, DD, w, lm, lq, acc, 8);
#pragma unroll
    for (int nb = 0; nb < 8; ++nb) {
        float bv = bout[nb * 16 + lm];
#pragma unroll
        for (int r = 0; r < 4; ++r)
            Yg[(long)(w * 16 + lq * 4 + r) * DD + nb * 16 + lm] = acc[nb][r] + bv;
    }
}

extern "C" void kernel_launch(void* const* d_in, const int* in_sizes, int n_in,
                              void* d_out, int out_size, void* d_ws, size_t ws_size,
                              hipStream_t stream) {
    const float* queries = (const float*)d_in[0];
    const float* keys    = (const float*)d_in[1];
    const int*   ccc     = (const int*)d_in[2];
    const float* Wq      = (const float*)d_in[3];
    const float* bq      = (const float*)d_in[4];
    const float* Wkv     = (const float*)d_in[5];
    const float* bkv     = (const float*)d_in[6];
    const float* Wout    = (const float*)d_in[7];
    const float* bout    = (const float*)d_in[8];
    float* out = (float*)d_out;

    float*  Wcomb = (float*)d_ws;                       // 16384 f32
    float*  bcomb = Wcomb + DD * DD;                    // 128 f32
    __bf16* Wb    = (__bf16*)((char*)d_ws + 66048);     // 4 x 16384 bf16 (Wq|Wkv|Wout|Wcomb)

    combine_w<<<dim3(128), dim3(128), 0, stream>>>(Wout, Wkv, bkv, bout, Wcomb, bcomb);
    cvt_weights<<<dim3(64), dim3(256), 0, stream>>>(Wq, Wkv, Wout, Wcomb, Wb);

    gemm_pass<<<dim3(BB * 32), dim3(256), 0, stream>>>(keys, Wb + 49152, bcomb, out);

    attn_kernel<<<dim3(BB * PP), dim3(256), 0, stream>>>(
        queries, keys, ccc, Wb, bq, bkv, bout, out);
}

// Round 3
// 252.688 us; speedup vs baseline: 5.1945x; 1.0376x over previous
//
#include <hip/hip_runtime.h>

#define BB 16
#define PP 96
#define TT 128
#define VV 64
#define NN 16
#define DD 128
#define BPP (BB * PP)     // 1536 attention blocks
#define NPASS (BB * 32)   // 512 passthrough blocks
#define SB 136            // bf16 row stride for q/Ks/O tiles (272 B, 16B-aligned)
#define ST 72             // KsT / A row stride (144 B, 16B-aligned)
#define SSF 68            // S f32 row stride (272 B = same bytes as SB)

typedef __bf16 bf16x8 __attribute__((ext_vector_type(8)));
typedef __bf16 bf16x4 __attribute__((ext_vector_type(4)));
typedef float  floatx4 __attribute__((ext_vector_type(4)));

#define MFMA16(a, b, c) __builtin_amdgcn_mfma_f32_16x16x32_bf16(a, b, c, 0, 0, 0)

__device__ __forceinline__ bf16x8 cvt8(float4 a, float4 b) {
    return bf16x8{(__bf16)a.x, (__bf16)a.y, (__bf16)a.z, (__bf16)a.w,
                  (__bf16)b.x, (__bf16)b.y, (__bf16)b.z, (__bf16)b.w};
}

// A-frags for a 16-row strip directly from global f32 (row stride DD).
// Wave access per ks: 16 rows x 128 B contiguous segments -> full-line coalesced.
__device__ __forceinline__ void loadA_g(const float* Xs, int lm, int lq, bf16x8 af[4]) {
    const float4* p = (const float4*)(Xs + lm * DD + lq * 8);
#pragma unroll
    for (int ks = 0; ks < 4; ++ks) af[ks] = cvt8(p[8 * ks], p[8 * ks + 1]);
}

// A-frags from LDS bf16 (row stride sa), kblocks k-chunks of 32
__device__ __forceinline__ void loadA_l(const __bf16* As, int sa, int lm, int lq,
                                        bf16x8* af, int kblocks) {
#pragma unroll
    for (int ks = 0; ks < 4; ++ks) {
        if (ks >= kblocks) break;
        af[ks] = *(const bf16x8*)(As + lm * sa + lq * 8 + 32 * ks);
    }
}

// acc[nb] = A_strip @ B^T ; B row-major bf16 stride sb (global weights or LDS)
__device__ __forceinline__ void mmB(const bf16x8* af, const __bf16* B, int sb,
                                    int lm, int lq, floatx4* acc, int nblocks, int kblocks) {
#pragma unroll
    for (int nb = 0; nb < 8; ++nb) {
        if (nb >= nblocks) break;
        acc[nb] = floatx4{0.f, 0.f, 0.f, 0.f};
#pragma unroll
        for (int ks = 0; ks < 4; ++ks) {
            if (ks >= kblocks) break;
            bf16x8 bf = *(const bf16x8*)(B + (nb * 16 + lm) * sb + lq * 8 + 32 * ks);
            acc[nb] = MFMA16(af[ks], bf, acc[nb]);
        }
    }
}

// ---------------------------------------------------------------------------
// prep: Wb = bf16{Wq | Wkv | Wout | Wcomb=Wout@Wkv}; bcomb = Wout@bkv + bout
// grid 128 x 128
// ---------------------------------------------------------------------------
__global__ void prep(const float* __restrict__ Wq, const float* __restrict__ Wkv,
                     const float* __restrict__ Wout, const float* __restrict__ bkv,
                     const float* __restrict__ bout,
                     __bf16* __restrict__ Wb, float* __restrict__ bcomb) {
    int i = blockIdx.x, j = threadIdx.x;
    Wb[i * DD + j]         = (__bf16)Wq[i * DD + j];
    Wb[16384 + i * DD + j] = (__bf16)Wkv[i * DD + j];
    Wb[32768 + i * DD + j] = (__bf16)Wout[i * DD + j];
    float acc = 0.f;
    for (int k = 0; k < DD; ++k) acc += Wout[i * DD + k] * Wkv[k * DD + j];  // coalesced over j
    Wb[49152 + i * DD + j] = (__bf16)acc;
    if (i == 0) {
        float bs = bout[j];
        for (int k = 0; k < DD; ++k) bs += Wout[j * DD + k] * bkv[k];
        bcomb[j] = bs;
    }
}

// ---------------------------------------------------------------------------
// fused: blocks [0,1536) = attention per (b,p); [1536,2048) = passthrough.
// 256 threads = 4 waves; wave w owns output rows [16w,16w+16).
// Barriers: 2 (all other phase chaining is wave-private via per-wave
// in-order LDS).
// ---------------------------------------------------------------------------
__global__ __launch_bounds__(256, 3) void fused(
    const float* __restrict__ queries, const float* __restrict__ keys,
    const int* __restrict__ ccc, const __bf16* __restrict__ Wb,
    const float* __restrict__ bq, const float* __restrict__ bkv,
    const float* __restrict__ bout, const float* __restrict__ bcomb,
    float* __restrict__ out) {
    __shared__ __align__(16) char lds[53248];
    __bf16* R1    = (__bf16*)lds;             // 17408: q -> S(f32) -> O
    __bf16* smKs  = (__bf16*)(lds + 17408);   // 17408: Ks -> A_sp
    __bf16* smKsT = (__bf16*)(lds + 34816);   // 18432: Ks^T (128 x 64)
    __bf16* smA   = smKs;
    float*  smS   = (float*)lds;

    int bl = blockIdx.x, t = threadIdx.x;
    int w = t >> 6, L = t & 63, lm = L & 15, lq = L >> 4;

    bf16x8 af[4];
    floatx4 acc[8];

    if (bl >= BPP) {
        // ---- passthrough: out[b, wi rows] = keys @ Wcomb^T + bcomb ----
        int pb = bl - BPP;
        int b = pb >> 5, wi = pb & 31;
        const float* Xs = keys + ((long)b * TT * VV + wi * 64 + w * 16) * DD;
        float* Yg = out + ((long)b * TT * VV + wi * 64) * DD;
        loadA_g(Xs, lm, lq, af);
        mmB(af, Wb + 49152, DD, lm, lq, acc, 8, 4);
#pragma unroll
        for (int nb = 0; nb < 8; ++nb) {
            float bv = bcomb[nb * 16 + lm];
#pragma unroll
            for (int r = 0; r < 4; ++r)
                Yg[(long)(w * 16 + lq * 4 + r) * DD + nb * 16 + lm] = acc[nb][r] + bv;
        }
        return;
    }

    int b = bl / PP, p = bl % PP;
    const float* Qg = queries + ((long)(b * PP + p) * VV) * DD;
    const float* Kg = keys + ((long)(b * TT + 32 + p) * VV) * DD;
    float* Yg = out + ((long)(b * TT + 32 + p) * VV) * DD;

    // ccc for this wave's strip rows (lanes L<16 own row v = 16w+L)
    int se[NN];
    if (L < 16) {
        const int4* cp = (const int4*)(ccc + ((long)b * VV + w * 16 + L) * NN);
#pragma unroll
        for (int i = 0; i < 4; ++i) {
            int4 c4 = cp[i];
            se[4 * i] = c4.x; se[4 * i + 1] = c4.y;
            se[4 * i + 2] = c4.z; se[4 * i + 3] = c4.w;
        }
    }

    // ---- P1: q = Q @ Wq^T + bq -> R1 strip (wave-private) ----
    loadA_g(Qg + w * 16 * DD, lm, lq, af);
    mmB(af, Wb, DD, lm, lq, acc, 8, 4);
#pragma unroll
    for (int nb = 0; nb < 8; ++nb) {
        float bv = bq[nb * 16 + lm];
#pragma unroll
        for (int r = 0; r < 4; ++r)
            R1[(w * 16 + lq * 4 + r) * SB + nb * 16 + lm] = (__bf16)(acc[nb][r] + bv);
    }

    // ---- P2: Ks = K @ Wkv^T + bkv -> smKs + smKsT ----
    loadA_g(Kg + w * 16 * DD, lm, lq, af);
    mmB(af, Wb + 16384, DD, lm, lq, acc, 8, 4);
#pragma unroll
    for (int nb = 0; nb < 8; ++nb) {
        float bv = bkv[nb * 16 + lm];
        bf16x4 tp;
#pragma unroll
        for (int r = 0; r < 4; ++r) {
            float vv = acc[nb][r] + bv;
            smKs[(w * 16 + lq * 4 + r) * SB + nb * 16 + lm] = (__bf16)vv;
            tp[r] = (__bf16)vv;
        }
        *(bf16x4*)(smKsT + (nb * 16 + lm) * ST + w * 16 + lq * 4) = tp;
    }
    __syncthreads();  // B1: publish Ks/KsT

    // ---- P3: S = q @ Ks^T (f32, written over q strip; af read first) ----
    loadA_l(R1 + w * 16 * SB, SB, lm, lq, af, 4);
    mmB(af, smKs, SB, lm, lq, acc, 4, 4);
#pragma unroll
    for (int nb = 0; nb < 4; ++nb)
#pragma unroll
        for (int r = 0; r < 4; ++r)
            smS[(w * 16 + lq * 4 + r) * SSF + nb * 16 + lm] = acc[nb][r];
    __syncthreads();  // B2: all smKs reads done before A_sp alias reuse

    // ---- P4: zero A strip; gather+softmax+scatter (wave-private rows) ----
    {
        unsigned* za = (unsigned*)(smA + (w * 16) * ST);
        for (int i = L; i < 16 * ST / 2; i += 64) za[i] = 0u;
        if (L < 16) {
            int v = w * 16 + L;
            float sc[NN], mx = -1e30f;
#pragma unroll
            for (int n = 0; n < NN; ++n) {
                sc[n] = smS[v * SSF + se[n]] * 0.08838834764831845f;
                mx = fmaxf(mx, sc[n]);
            }
            float sum = 0.f;
#pragma unroll
            for (int n = 0; n < NN; ++n) { sc[n] = __expf(sc[n] - mx); sum += sc[n]; }
            float inv = 1.f / sum;
#pragma unroll
            for (int n = 0; n < NN; ++n) {  // dup-safe: one lane per row, serial RMW
                int u = se[n];
                smA[v * ST + u] = (__bf16)((float)smA[v * ST + u] + sc[n] * inv);
            }
        }
    }
    // no barrier: P5 reads A rows [16w,16w+16) written by this wave (in-order LDS)

    // ---- P5: O = A_sp @ Ks (B-frags from KsT), K=64 -> R1 strip ----
    loadA_l(smA + w * 16 * ST, ST, lm, lq, af, 2);
    mmB(af, smKsT, ST, lm, lq, acc, 8, 2);
#pragma unroll
    for (int nb = 0; nb < 8; ++nb)
#pragma unroll
        for (int r = 0; r < 4; ++r)
            R1[(w * 16 + lq * 4 + r) * SB + nb * 16 + lm] = (__bf16)acc[nb][r];

    // ---- P6: Y = O @ Wout^T + bout -> global (same-wave strip) ----
    loadA_l(R1 + w * 16 * SB, SB, lm, lq, af, 4);
    mmB(af, Wb + 32768, DD, lm, lq, acc, 8, 4);
#pragma unroll
    for (int nb = 0; nb < 8; ++nb) {
        float bv = bout[nb * 16 + lm];
#pragma unroll
        for (int r = 0; r < 4; ++r)
            Yg[(long)(w * 16 + lq * 4 + r) * DD + nb * 16 + lm] = acc[nb][r] + bv;
    }
}

extern "C" void kernel_launch(void* const* d_in, const int* in_sizes, int n_in,
                              void* d_out, int out_size, void* d_ws, size_t ws_size,
                              hipStream_t stream) {
    const float* queries = (const float*)d_in[0];
    const float* keys    = (const float*)d_in[1];
    const int*   ccc     = (const int*)d_in[2];
    const float* Wq      = (const float*)d_in[3];
    const float* bq      = (const float*)d_in[4];
    const float* Wkv     = (const float*)d_in[5];
    const float* bkv     = (const float*)d_in[6];
    const float* Wout    = (const float*)d_in[7];
    const float* bout    = (const float*)d_in[8];
    float* out = (float*)d_out;

    __bf16* Wb    = (__bf16*)d_ws;                        // 4 x 16384 bf16 = 128 KB
    float*  bcomb = (float*)((char*)d_ws + 131072);       // 128 f32

    prep<<<dim3(128), dim3(128), 0, stream>>>(Wq, Wkv, Wout, bkv, bout, Wb, bcomb);

    fused<<<dim3(BPP + NPASS), dim3(256), 0, stream>>>(
        queries, keys, ccc, Wb, bq, bkv, bout, bcomb, out);
}

// Round 4
// 240.840 us; speedup vs baseline: 5.4500x; 1.0492x over previous
//
#include <hip/hip_runtime.h>

#define BB 16
#define PP 96
#define TT 128
#define VV 64
#define NN 16
#define DD 128
#define BPP (BB * PP)     // 1536 attention blocks
#define NPASS (BB * 32)   // 512 passthrough blocks
#define SB 136            // bf16 row stride for q/Ks/O tiles (272 B)
#define ST 72             // KsT / A row stride (144 B)
#define SSF 68            // S f32 row stride (272 B = same bytes as SB)
#define SCALE 0.08838834764831845f
#define SLICE 4352        // per-wave byte slice in region1 (= 16 rows * 272 B)

typedef __bf16 bf16x8 __attribute__((ext_vector_type(8)));
typedef __bf16 bf16x4 __attribute__((ext_vector_type(4)));
typedef float  floatx4 __attribute__((ext_vector_type(4)));

#define MFMA16(a, b, c) __builtin_amdgcn_mfma_f32_16x16x32_bf16(a, b, c, 0, 0, 0)

__device__ __forceinline__ bf16x8 cvt8(float4 a, float4 b) {
    return bf16x8{(__bf16)a.x, (__bf16)a.y, (__bf16)a.z, (__bf16)a.w,
                  (__bf16)b.x, (__bf16)b.y, (__bf16)b.z, (__bf16)b.w};
}

// A-frags for a 16-row strip directly from global f32 (row stride DD).
__device__ __forceinline__ void loadA_g(const float* Xs, int lm, int lq, bf16x8 af[4]) {
    const float4* p = (const float4*)(Xs + lm * DD + lq * 8);
#pragma unroll
    for (int ks = 0; ks < 4; ++ks) af[ks] = cvt8(p[8 * ks], p[8 * ks + 1]);
}

// A-frags from LDS bf16 (row stride sa), kblocks k-chunks of 32
__device__ __forceinline__ void loadA_l(const __bf16* As, int sa, int lm, int lq,
                                        bf16x8* af, int kblocks) {
#pragma unroll
    for (int ks = 0; ks < 4; ++ks) {
        if (ks >= kblocks) break;
        af[ks] = *(const bf16x8*)(As + lm * sa + lq * 8 + 32 * ks);
    }
}

// acc[nb] = A_strip @ B^T ; B row-major bf16 stride sb (global weights or LDS)
__device__ __forceinline__ void mmB(const bf16x8* af, const __bf16* B, int sb,
                                    int lm, int lq, floatx4* acc, int nblocks, int kblocks) {
#pragma unroll
    for (int nb = 0; nb < 8; ++nb) {
        if (nb >= nblocks) break;
        acc[nb] = floatx4{0.f, 0.f, 0.f, 0.f};
#pragma unroll
        for (int ks = 0; ks < 4; ++ks) {
            if (ks >= kblocks) break;
            bf16x8 bf = *(const bf16x8*)(B + (nb * 16 + lm) * sb + lq * 8 + 32 * ks);
            acc[nb] = MFMA16(af[ks], bf, acc[nb]);
        }
    }
}

// ---------------------------------------------------------------------------
// prep: Wb = bf16{Wq | Wkv | Wout | Wcomb=Wout@Wkv}; bcomb = Wout@bkv + bout
// ---------------------------------------------------------------------------
__global__ void prep(const float* __restrict__ Wq, const float* __restrict__ Wkv,
                     const float* __restrict__ Wout, const float* __restrict__ bkv,
                     const float* __restrict__ bout,
                     __bf16* __restrict__ Wb, float* __restrict__ bcomb) {
    int i = blockIdx.x, j = threadIdx.x;
    Wb[i * DD + j]         = (__bf16)Wq[i * DD + j];
    Wb[16384 + i * DD + j] = (__bf16)Wkv[i * DD + j];
    Wb[32768 + i * DD + j] = (__bf16)Wout[i * DD + j];
    float acc = 0.f;
    for (int k = 0; k < DD; ++k) acc += Wout[i * DD + k] * Wkv[k * DD + j];
    Wb[49152 + i * DD + j] = (__bf16)acc;
    if (i == 0) {
        float bs = bout[j];
        for (int k = 0; k < DD; ++k) bs += Wout[j * DD + k] * bkv[k];
        bcomb[j] = bs;
    }
}

// ---------------------------------------------------------------------------
// fused: blocks [0,1536) = attention per (b,p); [1536,2048) = passthrough.
// 4 waves; wave w owns output rows [16w,16w+16). ONE barrier per block.
// Region1 (per-wave 4352 B slices): q strip -> S strip(f32) -> A strip -> O strip,
// all wave-private, correctness via per-wave in-order LDS.
// ---------------------------------------------------------------------------
__global__ __launch_bounds__(256, 3) void fused(
    const float* __restrict__ queries, const float* __restrict__ keys,
    const int* __restrict__ ccc, const __bf16* __restrict__ Wb,
    const float* __restrict__ bq, const float* __restrict__ bkv,
    const float* __restrict__ bout, const float* __restrict__ bcomb,
    float* __restrict__ out) {
    __shared__ __align__(16) char lds[53248];
    __bf16* R1    = (__bf16*)lds;             // 17408: q / S(f32) / A / O (per-wave slices)
    __bf16* smKs  = (__bf16*)(lds + 17408);   // 17408: Ks row-major
    __bf16* smKsT = (__bf16*)(lds + 34816);   // 18432: Ks^T (128 x 64)
    float*  smS   = (float*)lds;

    int bl = blockIdx.x, t = threadIdx.x;
    int w = t >> 6, L = t & 63, lm = L & 15, lq = L >> 4;

    bf16x8 af[4];
    floatx4 acc[8];

    if (bl >= BPP) {
        // ---- passthrough: out[b, wi rows] = keys @ Wcomb^T + bcomb ----
        int pb = bl - BPP;
        int b = pb >> 5, wi = pb & 31;
        const float* Xs = keys + ((long)b * TT * VV + wi * 64 + w * 16) * DD;
        float* Yg = out + ((long)b * TT * VV + wi * 64) * DD;
        loadA_g(Xs, lm, lq, af);
        mmB(af, Wb + 49152, DD, lm, lq, acc, 8, 4);
#pragma unroll
        for (int nb = 0; nb < 8; ++nb) {
            float bv = bcomb[nb * 16 + lm];
#pragma unroll
            for (int r = 0; r < 4; ++r)
                Yg[(long)(w * 16 + lq * 4 + r) * DD + nb * 16 + lm] = acc[nb][r] + bv;
        }
        return;
    }

    int b = bl / PP, p = bl % PP;
    const float* Qg = queries + ((long)(b * PP + p) * VV) * DD;
    const float* Kg = keys + ((long)(b * TT + 32 + p) * VV) * DD;
    float* Yg = out + ((long)(b * TT + 32 + p) * VV) * DD;

    // ---- P0: prefetch Q strip + K strip + ccc row (all HBM loads in flight) ----
    float4 qr[8], kr[8];
    {
        const float4* qp = (const float4*)(Qg + (w * 16 + lm) * DD + lq * 8);
        const float4* kp = (const float4*)(Kg + (w * 16 + lm) * DD + lq * 8);
#pragma unroll
        for (int ks = 0; ks < 4; ++ks) {
            qr[2 * ks] = qp[8 * ks]; qr[2 * ks + 1] = qp[8 * ks + 1];
            kr[2 * ks] = kp[8 * ks]; kr[2 * ks + 1] = kp[8 * ks + 1];
        }
    }
    // every lane loads ALL 16 indices of its row v = w*16 + (L&15)
    int se[NN];
    {
        const int4* cp = (const int4*)(ccc + ((long)b * VV + w * 16 + lm) * NN);
#pragma unroll
        for (int i = 0; i < 4; ++i) {
            int4 c4 = cp[i];
            se[4 * i] = c4.x; se[4 * i + 1] = c4.y;
            se[4 * i + 2] = c4.z; se[4 * i + 3] = c4.w;
        }
    }

    // ---- P1: q = Q @ Wq^T + bq -> q strip (wave-private slice) ----
#pragma unroll
    for (int ks = 0; ks < 4; ++ks) af[ks] = cvt8(qr[2 * ks], qr[2 * ks + 1]);
    mmB(af, Wb, DD, lm, lq, acc, 8, 4);
#pragma unroll
    for (int nb = 0; nb < 8; ++nb) {
        float bv = bq[nb * 16 + lm];
#pragma unroll
        for (int r = 0; r < 4; ++r)
            R1[(w * 16 + lq * 4 + r) * SB + nb * 16 + lm] = (__bf16)(acc[nb][r] + bv);
    }

    // ---- P2: Ks = K @ Wkv^T + bkv -> smKs + smKsT ----
#pragma unroll
    for (int ks = 0; ks < 4; ++ks) af[ks] = cvt8(kr[2 * ks], kr[2 * ks + 1]);
    mmB(af, Wb + 16384, DD, lm, lq, acc, 8, 4);
#pragma unroll
    for (int nb = 0; nb < 8; ++nb) {
        float bv = bkv[nb * 16 + lm];
        bf16x4 tp;
#pragma unroll
        for (int r = 0; r < 4; ++r) {
            float vv = acc[nb][r] + bv;
            smKs[(w * 16 + lq * 4 + r) * SB + nb * 16 + lm] = (__bf16)vv;
            tp[r] = (__bf16)vv;
        }
        *(bf16x4*)(smKsT + (nb * 16 + lm) * ST + w * 16 + lq * 4) = tp;
    }
    __syncthreads();  // B1: publish Ks/KsT (the ONLY barrier)

    // ---- P3: S = q @ Ks^T (f32) -> S strip over q slice (af read first) ----
    loadA_l(R1 + w * 16 * SB, SB, lm, lq, af, 4);
    mmB(af, smKs, SB, lm, lq, acc, 4, 4);
#pragma unroll
    for (int nb = 0; nb < 4; ++nb)
#pragma unroll
        for (int r = 0; r < 4; ++r)
            smS[(w * 16 + lq * 4 + r) * SSF + nb * 16 + lm] = acc[nb][r];

    // ---- P4: softmax + dup-total scatter, all 64 lanes, no RMW, no barrier ----
    __bf16* smAsl = (__bf16*)(lds + w * SLICE);  // A strip: 16 rows x ST bf16
    {
        int g = lq;  // lane handles row lm, n-quad g
        float sg[NN];
        const float* Srow = smS + (w * 16 + lm) * SSF;
#pragma unroll
        for (int n = 0; n < NN; ++n) sg[n] = Srow[se[n]];  // reads issued first
        // zero A strip (writes ordered after reads: per-wave in-order LDS)
        unsigned* za = (unsigned*)smAsl;
        for (int i = L; i < 16 * ST / 2; i += 64) za[i] = 0u;
        float mx = -1e30f;
#pragma unroll
        for (int n = 0; n < NN; ++n) { sg[n] *= SCALE; mx = fmaxf(mx, sg[n]); }
        float sum = 0.f;
#pragma unroll
        for (int n = 0; n < NN; ++n) { sg[n] = __expf(sg[n] - mx); sum += sg[n]; }
        float inv = 1.f / sum;
#pragma unroll
        for (int j = 0; j < 4; ++j) {  // dup groups write identical totals
            int u = se[g * 4 + j];
            float tot = 0.f;
#pragma unroll
            for (int n = 0; n < NN; ++n) tot += (se[n] == u) ? sg[n] : 0.f;
            smAsl[lm * ST + u] = (__bf16)(tot * inv);
        }
    }

    // ---- P5: O = A_sp @ Ks (B from KsT), K=64 -> O strip over slice ----
    loadA_l(smAsl, ST, lm, lq, af, 2);
    mmB(af, smKsT, ST, lm, lq, acc, 8, 2);
#pragma unroll
    for (int nb = 0; nb < 8; ++nb)
#pragma unroll
        for (int r = 0; r < 4; ++r)
            R1[(w * 16 + lq * 4 + r) * SB + nb * 16 + lm] = (__bf16)acc[nb][r];

    // ---- P6: Y = O @ Wout^T + bout -> global (same-wave strip) ----
    loadA_l(R1 + w * 16 * SB, SB, lm, lq, af, 4);
    mmB(af, Wb + 32768, DD, lm, lq, acc, 8, 4);
#pragma unroll
    for (int nb = 0; nb < 8; ++nb) {
        float bv = bout[nb * 16 + lm];
#pragma unroll
        for (int r = 0; r < 4; ++r)
            Yg[(long)(w * 16 + lq * 4 + r) * DD + nb * 16 + lm] = acc[nb][r] + bv;
    }
}

extern "C" void kernel_launch(void* const* d_in, const int* in_sizes, int n_in,
                              void* d_out, int out_size, void* d_ws, size_t ws_size,
                              hipStream_t stream) {
    const float* queries = (const float*)d_in[0];
    const float* keys    = (const float*)d_in[1];
    const int*   ccc     = (const int*)d_in[2];
    const float* Wq      = (const float*)d_in[3];
    const float* bq      = (const float*)d_in[4];
    const float* Wkv     = (const float*)d_in[5];
    const float* bkv     = (const float*)d_in[6];
    const float* Wout    = (const float*)d_in[7];
    const float* bout    = (const float*)d_in[8];
    float* out = (float*)d_out;

    __bf16* Wb    = (__bf16*)d_ws;                        // 4 x 16384 bf16 = 128 KB
    float*  bcomb = (float*)((char*)d_ws + 131072);       // 128 f32

    prep<<<dim3(128), dim3(128), 0, stream>>>(Wq, Wkv, Wout, bkv, bout, Wb, bcomb);

    fused<<<dim3(BPP + NPASS), dim3(256), 0, stream>>>(
        queries, keys, ccc, Wb, bq, bkv, bout, bcomb, out);
}